// Round 20
// baseline (247.312 us; speedup 1.0000x reference)
//
#include <hip/hip_runtime.h>
#include <hip/hip_bf16.h>
#include <math.h>

#define BB 16
#define SS 4096
#define IN 64
#define DD 256
#define NN 16
#define KK 32
#define CH 64
#define LCH 64
#define BS (BB*SS)

typedef __attribute__((ext_vector_type(4))) float f32x4;
typedef __attribute__((ext_vector_type(8))) short bf16x8;

__device__ __forceinline__ float bf2f(unsigned short u){
  return __uint_as_float(((unsigned int)u)<<16);
}
__device__ __forceinline__ unsigned short f2bf(float f){
  unsigned int u = __float_as_uint(f);
  return (unsigned short)((u + 0x7fffu + ((u>>16)&1u)) >> 16);
}
__device__ __forceinline__ float fast_softplus(float v){
  float e = __expf(-fabsf(v));
  return fmaxf(v, 0.f) + __logf(1.f + e);
}
__device__ __forceinline__ float fast_silu(float v){
  return v * __builtin_amdgcn_rcpf(1.f + __expf(-v));
}
// XOR-swizzled LDS addressing for 64x(256 bf16) tiles (512B rows).
__device__ __forceinline__ void* swz(void* base, int row, int byteoff){
  return (void*)((char*)base + (row<<9) + (byteoff ^ ((row&7)<<4)));
}
// FFT LDS swizzle on float2 index.
#define SW(i) ((i) ^ (((i)>>4)&15))
// base-4 digit reversal of a 12-bit index (6 digits).
__device__ __forceinline__ int rev4(int k){
  return ((k&3)<<10) | (((k>>2)&3)<<8) | (((k>>4)&3)<<6)
       | (((k>>6)&3)<<4) | (((k>>8)&3)<<2) | ((k>>10)&3);
}

// ---------------- prep: fragment-major bf16 weights (Wd+Wbc, Wg, W_in), twiddles ----------------
__global__ void k_prep(const float* Wd, const float* Wg, const float* WB, const float* WC,
                       const float* W_in, const float* bBv, const float* bCv,
                       unsigned short* WdF, unsigned short* WgF, unsigned short* WinF,
                       float* bbc, float2* tw){
  int id = blockIdx.x*256 + threadIdx.x;
  if (id < 73728){
    int jn = id >> 12; int rem = id & 4095;
    int kc = rem >> 9; int l8 = (rem >> 3) & 63; int e = id & 7;
    int lr = l8 & 15, lh = l8 >> 4;
    int k = kc*32 + lh*8 + e;
    float v;
    if (jn < 16){ int n = jn*16 + lr; v = Wd[k*256+n]; }
    else { int c = (jn-16)*16 + lr; v = (c<16) ? WB[k*16+c] : WC[k*16+(c-16)]; }
    WdF[id] = f2bf(v);
  }
  else if (id < 139264){
    int o = id - 73728;
    int jn = o >> 12; int rem = o & 4095;
    int kc = rem >> 9; int l8 = (rem >> 3) & 63; int e = o & 7;
    int lr = l8 & 15, lh = l8 >> 4;
    int k = kc*32 + lh*8 + e;
    WgF[o] = f2bf(Wg[k*256 + jn*16 + lr]);
  }
  else if (id < 155648){
    int o = id - 139264;
    int jn = o >> 10; int rem = o & 1023;
    int kc = rem >> 9; int l8 = (rem >> 3) & 63; int e = o & 7;
    int lr = l8 & 15, lh = l8 >> 4;
    int k = kc*32 + lh*8 + e;
    WinF[o] = f2bf(W_in[k*256 + jn*16 + lr]);
  }
  else if (id < 157696){ int k = id-155648;
    double a = -6.283185307179586476925287 * (double)k / 4096.0;
    tw[k] = make_float2((float)cos(a), (float)sin(a)); }
  else if (id < 157728){ int j = id-157696; bbc[j] = (j<16)? bBv[j] : bCv[j-16]; }
}

// ---------------- fused front-end: MFMA xp GEMM + transposed xpz write + LN + conv + silu ----------------
__global__ __launch_bounds__(256,6) void k_front(const float* x, const unsigned short* WinF, const float* b_in,
      const float* ln1_g, const float* ln1_b, const float* conv_w, const float* conv_b,
      float2* xpz, unsigned short* xn16, unsigned short* u16){
  __shared__ unsigned short xb[32*64];
  __shared__ float xs[20][260];
  int tid = threadIdx.x;
  int b = blockIdx.y; int t0 = blockIdx.x*16;
  {
    int row = tid>>3, slot = tid&7;
    int t = t0 - 1 + row;
    unsigned short h[8];
    if (row < 18 && t >= 0 && t < SS){
      const float* src = &x[((size_t)b*SS + t)*IN + slot*8];
      float4 v0 = *(const float4*)src;
      float4 v1 = *(const float4*)(src+4);
      h[0]=f2bf(v0.x); h[1]=f2bf(v0.y); h[2]=f2bf(v0.z); h[3]=f2bf(v0.w);
      h[4]=f2bf(v1.x); h[5]=f2bf(v1.y); h[6]=f2bf(v1.z); h[7]=f2bf(v1.w);
    } else {
      #pragma unroll
      for (int i=0;i<8;i++) h[i]=0;
    }
    *(uint4*)&xb[row*64 + ((slot ^ (row&7))<<3)] = *(uint4*)h;
  }
  __syncthreads();
  int wv = tid>>6, lane = tid&63, lr = lane&15, lh = lane>>4;
  {
    bf16x8 af[2][2];
    #pragma unroll
    for (int rf=0;rf<2;rf++)
      #pragma unroll
      for (int kc=0;kc<2;kc++){
        int row = rf*16 + lr;
        int slot = (kc*4 + lh) ^ (row&7);
        af[rf][kc] = *(const bf16x8*)&xb[row*64 + slot*8];
      }
    f32x4 acc[2][4];
    #pragma unroll
    for (int rf=0;rf<2;rf++)
      #pragma unroll
      for (int jj=0;jj<4;jj++){ acc[rf][jj][0]=0.f; acc[rf][jj][1]=0.f; acc[rf][jj][2]=0.f; acc[rf][jj][3]=0.f; }
    #pragma unroll
    for (int jj=0;jj<4;jj++){
      int jn = wv*4 + jj;
      const bf16x8* bp = (const bf16x8*)(WinF + (size_t)jn*1024 + (size_t)lane*8);
      bf16x8 b0 = bp[0];
      bf16x8 b1 = bp[64];
      #pragma unroll
      for (int rf=0;rf<2;rf++){
        acc[rf][jj] = __builtin_amdgcn_mfma_f32_16x16x32_bf16(af[rf][0], b0, acc[rf][jj], 0,0,0);
        acc[rf][jj] = __builtin_amdgcn_mfma_f32_16x16x32_bf16(af[rf][1], b1, acc[rf][jj], 0,0,0);
      }
    }
    #pragma unroll
    for (int jj=0;jj<4;jj++){
      int col = (wv*4+jj)*16 + lr;
      float bs = b_in[col];
      #pragma unroll
      for (int rf=0;rf<2;rf++){
        #pragma unroll
        for (int i=0;i<4;i++){
          int row = rf*16 + lh*4 + i;
          if (row < 18) xs[row][col] = acc[rf][jj][i] + bs;
        }
      }
    }
  }
  __syncthreads();
  {
    int sl = tid&15, p0 = tid>>4;
    float2* dst = xpz + (size_t)b*128*SS + t0 + sl;
    #pragma unroll
    for (int pass=0; pass<8; pass++){
      int p = p0 + 16*pass;
      float2 v = *(const float2*)&xs[1+sl][2*p];
      dst[(size_t)p*SS] = v;
    }
  }
  __syncthreads();
  float4 lg4 = *(const float4*)&ln1_g[lane*4];
  float4 lb4 = *(const float4*)&ln1_b[lane*4];
  for (int r=wv; r<18; r+=4){
    int t = t0 - 1 + r;
    bool valid = (t>=0) && (t<SS);
    float4 v = *(const float4*)&xs[r][lane*4];
    float s1 = v.x+v.y+v.z+v.w;
    float s2 = v.x*v.x+v.y*v.y+v.z*v.z+v.w*v.w;
    #pragma unroll
    for (int off=32; off; off>>=1){ s1 += __shfl_xor(s1,off); s2 += __shfl_xor(s2,off); }
    float mean = s1*(1.f/256.f);
    float var  = s2*(1.f/256.f) - mean*mean;
    float rstd = rsqrtf(var + 1e-5f);
    float o0 = valid ? ((v.x-mean)*rstd*lg4.x + lb4.x) : 0.f;
    float o1 = valid ? ((v.y-mean)*rstd*lg4.y + lb4.y) : 0.f;
    float o2 = valid ? ((v.z-mean)*rstd*lg4.z + lb4.z) : 0.f;
    float o3 = valid ? ((v.w-mean)*rstd*lg4.w + lb4.w) : 0.f;
    *(float4*)&xs[r][lane*4] = make_float4(o0,o1,o2,o3);
    if (r>=1 && r<=16){
      ushort4 st;
      st.x=f2bf(o0); st.y=f2bf(o1); st.z=f2bf(o2); st.w=f2bf(o3);
      *(ushort4*)&xn16[((size_t)b*SS + t)*DD + lane*4] = st;
    }
  }
  __syncthreads();
  int d = tid;
  float w0=conv_w[d*3], w1=conv_w[d*3+1], w2=conv_w[d*3+2], cb=conv_b[d];
  #pragma unroll 4
  for (int rr=0; rr<16; rr++){
    float a0=xs[rr][d], a1=xs[rr+1][d], a2=xs[rr+2][d];
    float xc = a0*w0 + a1*w1 + a2*w2 + cb;
    u16[((size_t)b*SS + (t0+rr))*DD + d] = f2bf(fast_silu(xc));
  }
}

// ---------------- fused single-pass GEMM: 64 rows x all-N, A in LDS, frag-major B from L2 ----------------
// ACT==1 (u -> delta): writes t-paired de2/du2 (uint: 2 bf16 per word) + bc16.
// ACT==2 (xn -> g): writes t-paired g2.
template<int NTOT, int ACT>
__global__ __launch_bounds__(512,6) void k_gemm2(const unsigned short* Ab, const unsigned short* Bt,
      const float* bias_main, const float* bias_bc,
      unsigned int* out2, unsigned int* du2, unsigned short* out_bc){
  __shared__ unsigned short As[64*256];   // 32 KiB
  const int NF = NTOT/2;
  int tid = threadIdx.x;
  int m0 = blockIdx.x*64;
  {
    const uint4* gA = (const uint4*)(Ab + (size_t)m0*256);
    #pragma unroll
    for (int i=0;i<4;i++){
      int f = tid + 512*i;
      uint4 v = gA[f];
      *(uint4*)swz(As, f>>5, (f&31)<<4) = v;
    }
  }
  __syncthreads();
  int wv = tid>>6, lane = tid&63;
  int wm = wv>>1, nh = wv&1;
  int lr = lane&15, lh = lane>>4;
  const bf16x8* bbase = (const bf16x8*)(Bt + (size_t)(nh*NF)*4096 + (size_t)lane*8);
  bf16x8 af[8];
  #pragma unroll
  for (int kc=0;kc<8;kc++)
    af[kc] = *(const bf16x8*)swz(As, wm*16+lr, kc*64+lh*16);
  f32x4 acc[NF];
  #pragma unroll
  for (int j=0;j<NF;j++){ acc[j][0]=0.f; acc[j][1]=0.f; acc[j][2]=0.f; acc[j][3]=0.f; }
  bf16x8 bq[2][8];
  #pragma unroll
  for (int kc=0;kc<8;kc++) bq[0][kc] = bbase[kc*64];
  #pragma unroll
  for (int j=0;j<NF;j++){
    if (j+1 < NF){
      #pragma unroll
      for (int kc=0;kc<8;kc++) bq[(j+1)&1][kc] = bbase[(j+1)*512 + kc*64];
    }
    #pragma unroll
    for (int kc=0;kc<8;kc++){
      acc[j] = __builtin_amdgcn_mfma_f32_16x16x32_bf16(af[kc], bq[j&1][kc], acc[j], 0,0,0);
    }
  }
  int row0 = m0 + wm*16 + lh*4;           // global flat row (b*4096+t), t multiple of 4
  size_t pbase = ((size_t)row0 >> 1) * 256;   // pair index * 256
  #pragma unroll
  for (int j=0;j<NF;j++){
    int jn = nh*NF + j;
    if (jn < 16){
      int col = jn*16 + lr;
      float bs = bias_main[col];
      if (ACT==1){
        float de[4], du[4];
        #pragma unroll
        for (int i=0;i<4;i++){
          de[i] = fast_softplus(acc[j][i] + bs);
          float uu = bf2f(*(const unsigned short*)swz(As, wm*16+lh*4+i, col*2));
          du[i] = de[i]*uu;
        }
        out2[pbase + col]       = (unsigned int)f2bf(de[0]) | ((unsigned int)f2bf(de[1])<<16);
        out2[pbase + 256 + col] = (unsigned int)f2bf(de[2]) | ((unsigned int)f2bf(de[3])<<16);
        du2 [pbase + col]       = (unsigned int)f2bf(du[0]) | ((unsigned int)f2bf(du[1])<<16);
        du2 [pbase + 256 + col] = (unsigned int)f2bf(du[2]) | ((unsigned int)f2bf(du[3])<<16);
      } else {
        float g[4];
        #pragma unroll
        for (int i=0;i<4;i++) g[i] = fast_silu(acc[j][i] + bs);
        out2[pbase + col]       = (unsigned int)f2bf(g[0]) | ((unsigned int)f2bf(g[1])<<16);
        out2[pbase + 256 + col] = (unsigned int)f2bf(g[2]) | ((unsigned int)f2bf(g[3])<<16);
      }
    } else {
      int col = (jn-16)*16 + lr;
      float bs = bias_bc[col];
      #pragma unroll
      for (int i=0;i<4;i++){
        int row = m0 + wm*16 + lh*4 + i;
        out_bc[(size_t)row*32 + col] = f2bf(acc[j][i] + bs);
      }
    }
  }
}

// ---------------- FFT: two-for-one 4096-pt in-place radix-4 DIF; DC rank + T0 ----------------
__global__ __launch_bounds__(256,5) void k_fft(const float2* xpz, const float2* twg, int* rank, float* T0){
  __shared__ float2 buf[4096];
  __shared__ int scr8[8];
  int blk = blockIdx.x;
  int b = blk >> 7, pair = blk & 127;
  int tid = threadIdx.x;
  const float4* src4 = (const float4*)(xpz + ((size_t)b*128 + pair)*SS);
  #pragma unroll
  for (int q=tid; q<2048; q+=256){
    float4 v = src4[q];
    buf[SW(2*q)]   = make_float2(v.x, v.y);
    buf[SW(2*q+1)] = make_float2(v.z, v.w);
  }
  __syncthreads();
  int m = 1024, fac = 1;
  for (int st=0; st<6; st++){
    #pragma unroll
    for (int it=0; it<4; it++){
      int t = tid + 256*it;
      int j = t & (m-1);
      int i0 = 4*t - 3*j;
      float2 a0 = buf[SW(i0)];
      float2 a1 = buf[SW(i0+m)];
      float2 a2 = buf[SW(i0+2*m)];
      float2 a3 = buf[SW(i0+3*m)];
      float2 w1 = twg[j*fac];
      float2 w2 = make_float2(fmaf(w1.x,w1.x,-w1.y*w1.y), 2.f*w1.x*w1.y);
      float2 w3 = make_float2(fmaf(w1.x,w2.x,-w1.y*w2.y), fmaf(w1.x,w2.y, w1.y*w2.x));
      float t0x=a0.x+a2.x, t0y=a0.y+a2.y;
      float t1x=a0.x-a2.x, t1y=a0.y-a2.y;
      float t2x=a1.x+a3.x, t2y=a1.y+a3.y;
      float t3x=a1.y-a3.y, t3y=a3.x-a1.x;
      buf[SW(i0)]     = make_float2(t0x+t2x, t0y+t2y);
      float b1x = t1x+t3x, b1y = t1y+t3y;
      buf[SW(i0+m)]   = make_float2(fmaf(w1.x,b1x,-w1.y*b1y), fmaf(w1.x,b1y, w1.y*b1x));
      float b2x = t0x-t2x, b2y = t0y-t2y;
      buf[SW(i0+2*m)] = make_float2(fmaf(w2.x,b2x,-w2.y*b2y), fmaf(w2.x,b2y, w2.y*b2x));
      float b3x = t1x-t3x, b3y = t1y-t3y;
      buf[SW(i0+3*m)] = make_float2(fmaf(w3.x,b3x,-w3.y*b3y), fmaf(w3.x,b3y, w3.y*b3x));
    }
    __syncthreads();
    m >>= 2; fac <<= 2;
  }
  float2 z0 = buf[0];
  float thx = 4.f*z0.x*z0.x, thy = 4.f*z0.y*z0.y;
  int cx=0, cy=0;
  #pragma unroll
  for (int j=0;j<8;j++){
    int f = 1 + tid + 256*j;
    float2 zf = buf[SW(rev4(f))];
    float2 zc = buf[SW(rev4(4096-f))];
    float sxr = zf.x+zc.x, sxi = zf.y-zc.y;
    float syr = zf.x-zc.x, syi = zf.y+zc.y;
    cx += (fmaf(sxr,sxr,sxi*sxi) > thx) ? 1 : 0;
    cy += (fmaf(syr,syr,syi*syi) > thy) ? 1 : 0;
  }
  #pragma unroll
  for (int off=32; off; off>>=1){ cx += __shfl_xor(cx, off); cy += __shfl_xor(cy, off); }
  if ((tid&63)==0){ scr8[tid>>6] = cx; scr8[4+(tid>>6)] = cy; }
  __syncthreads();
  if (tid==0){
    int r0 = b*256 + 2*pair;
    rank[r0]   = scr8[0]+scr8[1]+scr8[2]+scr8[3];
    rank[r0+1] = scr8[4]+scr8[5]+scr8[6]+scr8[7];
    T0[r0]   = z0.x;
    T0[r0+1] = z0.y;
  }
}

// ---------------- scan pass A (d x n-half, f32 LDS bm, t-paired loads) ----------------
__global__ __launch_bounds__(512) void k_scanA(const unsigned int* de2, const unsigned int* du2,
      const unsigned short* bc16, const float* Aw, float* AB_A, float* AB_B){
  __shared__ float bcs[LCH][16];
  int c = blockIdx.x, b = blockIdx.y;
  int t0 = c*LCH;
  int tid = threadIdx.x;
  {
    int t = tid>>3, q = tid&7;
    unsigned int v = *(const unsigned int*)(bc16 + ((size_t)b*SS + t0 + t)*32 + q*2);
    bcs[t][q*2]   = bf2f((unsigned short)(v & 0xffff));
    bcs[t][q*2+1] = bf2f((unsigned short)(v >> 16));
  }
  __syncthreads();
  int d = tid & 255, hf = tid >> 8;
  float aw[8];
  #pragma unroll
  for (int j=0;j<2;j++){
    float4 a4 = *(const float4*)&Aw[d*16 + hf*8 + j*4];
    aw[4*j]=a4.x; aw[4*j+1]=a4.y; aw[4*j+2]=a4.z; aw[4*j+3]=a4.w;
  }
  float Ac[8], Bc[8];
  #pragma unroll
  for (int n=0;n<8;n++){ Ac[n]=1.f; Bc[n]=0.f; }
  const unsigned int* DE = de2 + ((size_t)b*2048 + c*32)*256 + d;
  const unsigned int* DU = du2 + ((size_t)b*2048 + c*32)*256 + d;
  #pragma unroll 4
  for (int p=0;p<32;p++){
    unsigned int dv = DE[(size_t)p*256];
    unsigned int uv = DU[(size_t)p*256];
    float de0 = __uint_as_float(dv<<16);
    float de1 = __uint_as_float(dv&0xffff0000u);
    float du0 = __uint_as_float(uv<<16);
    float du1 = __uint_as_float(uv&0xffff0000u);
    {
      float4 B0 = *(const float4*)&bcs[2*p][hf*8];
      float4 B1 = *(const float4*)&bcs[2*p][hf*8+4];
      float bm[8] = {B0.x,B0.y,B0.z,B0.w, B1.x,B1.y,B1.z,B1.w};
      #pragma unroll
      for (int n=0;n<8;n++){
        float a = fmaf(de0, aw[n], 1.f);
        Ac[n] *= a;
        Bc[n] = fmaf(a, Bc[n], du0*bm[n]);
      }
    }
    {
      float4 B0 = *(const float4*)&bcs[2*p+1][hf*8];
      float4 B1 = *(const float4*)&bcs[2*p+1][hf*8+4];
      float bm[8] = {B0.x,B0.y,B0.z,B0.w, B1.x,B1.y,B1.z,B1.w};
      #pragma unroll
      for (int n=0;n<8;n++){
        float a = fmaf(de1, aw[n], 1.f);
        Ac[n] *= a;
        Bc[n] = fmaf(a, Bc[n], du1*bm[n]);
      }
    }
  }
  size_t o = (size_t)c*65536 + (size_t)b*4096 + (size_t)d*16 + hf*8;
  #pragma unroll
  for (int j=0;j<2;j++){
    *(float4*)&AB_A[o+4*j] = make_float4(Ac[4*j],Ac[4*j+1],Ac[4*j+2],Ac[4*j+3]);
    *(float4*)&AB_B[o+4*j] = make_float4(Bc[4*j],Bc[4*j+1],Bc[4*j+2],Bc[4*j+3]);
  }
}

// ---------------- scan pass B: prefix over chunks ----------------
__global__ void k_scanB(const float* AB_A, const float* AB_B, float* Hs){
  int tid = blockIdx.x*256 + threadIdx.x;
  float h = 0.f;
  #pragma unroll 8
  for (int c=0;c<CH;c++){
    Hs[c*65536 + tid] = h;
    h = fmaf(AB_A[c*65536 + tid], h, AB_B[c*65536 + tid]);
  }
}

// ---------------- scan pass C (d x n-half, f32 LDS bm/cm, t-paired loads) ----------------
__global__ __launch_bounds__(512) void k_scanC(const unsigned int* de2, const unsigned int* du2,
      const unsigned int* g2, const unsigned short* bc16, const float* Aw, const float* Hs, float* part){
  __shared__ float bcs[LCH][32];
  __shared__ float scr[256];
  int c = blockIdx.x, b = blockIdx.y;
  int t0 = c*LCH;
  int tid = threadIdx.x;
  {
    int t = tid>>3, q = tid&7;
    uint2 v = *(const uint2*)(bc16 + ((size_t)b*SS + t0 + t)*32 + q*4);
    bcs[t][q*4]   = bf2f((unsigned short)(v.x & 0xffff));
    bcs[t][q*4+1] = bf2f((unsigned short)(v.x >> 16));
    bcs[t][q*4+2] = bf2f((unsigned short)(v.y & 0xffff));
    bcs[t][q*4+3] = bf2f((unsigned short)(v.y >> 16));
  }
  __syncthreads();
  int d = tid & 255, hf = tid >> 8;
  float aw[8];
  #pragma unroll
  for (int j=0;j<2;j++){
    float4 a4 = *(const float4*)&Aw[d*16 + hf*8 + j*4];
    aw[4*j]=a4.x; aw[4*j+1]=a4.y; aw[4*j+2]=a4.z; aw[4*j+3]=a4.w;
  }
  float h[8];
  {
    size_t o = (size_t)c*65536 + (size_t)b*4096 + (size_t)d*16 + hf*8;
    #pragma unroll
    for (int j=0;j<2;j++){
      float4 h4 = *(const float4*)&Hs[o+4*j];
      h[4*j]=h4.x; h[4*j+1]=h4.y; h[4*j+2]=h4.z; h[4*j+3]=h4.w;
    }
  }
  float acc = 0.f;
  const unsigned int* DE = de2 + ((size_t)b*2048 + c*32)*256 + d;
  const unsigned int* DU = du2 + ((size_t)b*2048 + c*32)*256 + d;
  const unsigned int* G  = g2  + ((size_t)b*2048 + c*32)*256 + d;
  #pragma unroll 4
  for (int p=0;p<32;p++){
    unsigned int dv = DE[(size_t)p*256];
    unsigned int uv = DU[(size_t)p*256];
    unsigned int gv = G [(size_t)p*256];
    float de0 = __uint_as_float(dv<<16);
    float de1 = __uint_as_float(dv&0xffff0000u);
    float du0 = __uint_as_float(uv<<16);
    float du1 = __uint_as_float(uv&0xffff0000u);
    float gg0 = __uint_as_float(gv<<16);
    float gg1 = __uint_as_float(gv&0xffff0000u);
    {
      float4 B0 = *(const float4*)&bcs[2*p][hf*8];
      float4 B1 = *(const float4*)&bcs[2*p][hf*8+4];
      float4 C0 = *(const float4*)&bcs[2*p][16+hf*8];
      float4 C1 = *(const float4*)&bcs[2*p][16+hf*8+4];
      float bm[8] = {B0.x,B0.y,B0.z,B0.w, B1.x,B1.y,B1.z,B1.w};
      float cm[8] = {C0.x,C0.y,C0.z,C0.w, C1.x,C1.y,C1.z,C1.w};
      float y0 = 0.f, y1 = 0.f;
      #pragma unroll
      for (int n=0;n<8;n+=2){
        float a0 = fmaf(de0, aw[n],   1.f);
        float a1 = fmaf(de0, aw[n+1], 1.f);
        h[n]   = fmaf(a0, h[n],   du0*bm[n]);
        h[n+1] = fmaf(a1, h[n+1], du0*bm[n+1]);
        y0 = fmaf(cm[n],   h[n],   y0);
        y1 = fmaf(cm[n+1], h[n+1], y1);
      }
      acc = fmaf(y0+y1, gg0, acc);
    }
    {
      float4 B0 = *(const float4*)&bcs[2*p+1][hf*8];
      float4 B1 = *(const float4*)&bcs[2*p+1][hf*8+4];
      float4 C0 = *(const float4*)&bcs[2*p+1][16+hf*8];
      float4 C1 = *(const float4*)&bcs[2*p+1][16+hf*8+4];
      float bm[8] = {B0.x,B0.y,B0.z,B0.w, B1.x,B1.y,B1.z,B1.w};
      float cm[8] = {C0.x,C0.y,C0.z,C0.w, C1.x,C1.y,C1.z,C1.w};
      float y0 = 0.f, y1 = 0.f;
      #pragma unroll
      for (int n=0;n<8;n+=2){
        float a0 = fmaf(de1, aw[n],   1.f);
        float a1 = fmaf(de1, aw[n+1], 1.f);
        h[n]   = fmaf(a0, h[n],   du1*bm[n]);
        h[n+1] = fmaf(a1, h[n+1], du1*bm[n+1]);
        y0 = fmaf(cm[n],   h[n],   y0);
        y1 = fmaf(cm[n+1], h[n+1], y1);
      }
      acc = fmaf(y0+y1, gg1, acc);
    }
  }
  if (hf==1) scr[d] = acc;
  __syncthreads();
  if (hf==0) part[(size_t)(b*256 + d)*CH + c] = acc + scr[d];
}

// ---------------- final: zp assembly + LN + 2-layer MLP ----------------
__global__ __launch_bounds__(256) void k_final(const float* part, const float* T0, const int* rank,
      const float* alpha, const float* beta, const float* filt_re,
      const float* lnc_g, const float* lnc_b,
      const float* W1, const float* b1, const float* W2, const float* b2,
      float* out){
  __shared__ float zs[256];
  __shared__ float h1[128];
  __shared__ float red[8];
  int b = blockIdx.x, d = threadIdx.x;
  int row = b*256 + d;
  float ps = 0.f;
  #pragma unroll 8
  for (int c=0;c<CH;c++) ps += part[(size_t)row*CH + c];
  float ssm_mean = ps * (1.f/4096.f);
  float t0v = T0[row];
  float mxp = t0v * (1.f/4096.f);
  int r = rank[row];
  float spec = (r < KK) ? t0v * filt_re[r*DD + d] * (1.f/4096.f) : 0.f;
  float zp = alpha[d]*(mxp + ssm_mean) + beta[d]*spec;
  float s1 = zp, s2 = zp*zp;
  #pragma unroll
  for (int off=32; off; off>>=1){ s1 += __shfl_xor(s1,off); s2 += __shfl_xor(s2,off); }
  if ((d&63)==0){ red[d>>6] = s1; red[4+(d>>6)] = s2; }
  __syncthreads();
  float mean = (red[0]+red[1]+red[2]+red[3]) * (1.f/256.f);
  float var  = (red[4]+red[5]+red[6]+red[7]) * (1.f/256.f) - mean*mean;
  float ln = (zp-mean)*rsqrtf(var+1e-5f)*lnc_g[d] + lnc_b[d];
  zs[d] = ln;
  __syncthreads();
  if (d < 128){
    float acc = b1[d];
    #pragma unroll 16
    for (int k=0;k<256;k++) acc = fmaf(zs[k], W1[k*128+d], acc);
    h1[d] = fmaxf(acc, 0.f);
  }
  __syncthreads();
  if (d < 2){
    float acc = b2[d];
    #pragma unroll 16
    for (int k=0;k<128;k++) acc = fmaf(h1[k], W2[k*2+d], acc);
    out[b*2+d] = acc;
  }
}

extern "C" void kernel_launch(void* const* d_in, const int* in_sizes, int n_in,
                              void* d_out, int out_size, void* d_ws, size_t ws_size,
                              hipStream_t stream){
  const float* x      = (const float*)d_in[0];
  const float* W_in   = (const float*)d_in[1];
  const float* b_in   = (const float*)d_in[2];
  const float* ln1_g  = (const float*)d_in[3];
  const float* ln1_b  = (const float*)d_in[4];
  const float* conv_w = (const float*)d_in[5];
  const float* conv_b = (const float*)d_in[6];
  const float* Wd     = (const float*)d_in[7];
  const float* bd     = (const float*)d_in[8];
  const float* WB     = (const float*)d_in[9];
  const float* bB     = (const float*)d_in[10];
  const float* WC     = (const float*)d_in[11];
  const float* bC     = (const float*)d_in[12];
  const float* A      = (const float*)d_in[13];
  const float* Wg     = (const float*)d_in[14];
  const float* bg     = (const float*)d_in[15];
  const float* filt_re= (const float*)d_in[16];
  const float* alpha  = (const float*)d_in[18];
  const float* beta   = (const float*)d_in[19];
  const float* lnc_g  = (const float*)d_in[20];
  const float* lnc_b  = (const float*)d_in[21];
  const float* W1     = (const float*)d_in[22];
  const float* b1     = (const float*)d_in[23];
  const float* W2     = (const float*)d_in[24];
  const float* b2     = (const float*)d_in[25];

  char* w = (char*)d_ws;
  unsigned int* de2 = (unsigned int*)(w);
  unsigned int* du2 = (unsigned int*)(w + 33554432);
  float2* xpz = (float2*)(w + 67108864);
  float* AB_A = (float*)(w + 67108864);
  float* AB_B = (float*)(w + 67108864 + 16777216);
  float* Hs   = (float*)(w + 67108864 + 33554432);
  unsigned short* bc16 = (unsigned short*)(w + 67108864 + 50331648);
  float* part = (float*)(w + 67108864 + 54525952);
  unsigned short* xn16 = (unsigned short*)(w + 134217728);
  unsigned short* u16  = (unsigned short*)(w + 167772160);
  unsigned int* g2 = (unsigned int*)(w + 201326592);
  char* small = w + 234881024;
  unsigned short* WdF  = (unsigned short*)(small);
  unsigned short* WgF  = (unsigned short*)(small + 147456);
  unsigned short* WinF = (unsigned short*)(small + 278528);
  float*  bbc = (float*)(small + 311296);
  float2* tw  = (float2*)(small + 311424);
  float*  T0  = (float*)(small + 327808);
  int*    rank= (int*)(small + 344192);
  (void)in_sizes; (void)n_in; (void)out_size; (void)ws_size;

  hipLaunchKernelGGL(k_prep, dim3(617), dim3(256), 0, stream,
                     Wd, Wg, WB, WC, W_in, bB, bC, WdF, WgF, WinF, bbc, tw);
  hipLaunchKernelGGL(k_front, dim3(SS/16, BB), dim3(256), 0, stream,
                     x, WinF, b_in, ln1_g, ln1_b, conv_w, conv_b, xpz, xn16, u16);
  hipLaunchKernelGGL(k_fft, dim3(BB*128), dim3(256), 0, stream, xpz, tw, rank, T0);
  hipLaunchKernelGGL((k_gemm2<18,1>), dim3(BS/64), dim3(512), 0, stream,
                     u16, WdF, bd, bbc, de2, du2, bc16);
  hipLaunchKernelGGL((k_gemm2<16,2>), dim3(BS/64), dim3(512), 0, stream,
                     xn16, WgF, bg, bbc, g2, (unsigned int*)nullptr, bc16);
  hipLaunchKernelGGL(k_scanA, dim3(CH, BB), dim3(512), 0, stream, de2, du2, bc16, A, AB_A, AB_B);
  hipLaunchKernelGGL(k_scanB, dim3(256), dim3(256), 0, stream, AB_A, AB_B, Hs);
  hipLaunchKernelGGL(k_scanC, dim3(CH, BB), dim3(512), 0, stream, de2, du2, g2, bc16, A, Hs, part);
  hipLaunchKernelGGL(k_final, dim3(BB), dim3(256), 0, stream,
                     part, T0, rank, alpha, beta, filt_re, lnc_g, lnc_b, W1, b1, W2, b2, (float*)d_out);
}

// Round 21
// 235.466 us; speedup vs baseline: 1.0503x; 1.0503x over previous
//
#include <hip/hip_runtime.h>
#include <hip/hip_bf16.h>
#include <math.h>

#define BB 16
#define SS 4096
#define IN 64
#define DD 256
#define NN 16
#define KK 32
#define CH 64
#define LCH 64
#define BS (BB*SS)

typedef __attribute__((ext_vector_type(4))) float f32x4;
typedef __attribute__((ext_vector_type(8))) short bf16x8;

__device__ __forceinline__ float bf2f(unsigned short u){
  return __uint_as_float(((unsigned int)u)<<16);
}
__device__ __forceinline__ unsigned short f2bf(float f){
  unsigned int u = __float_as_uint(f);
  return (unsigned short)((u + 0x7fffu + ((u>>16)&1u)) >> 16);
}
__device__ __forceinline__ float fast_softplus(float v){
  float e = __expf(-fabsf(v));
  return fmaxf(v, 0.f) + __logf(1.f + e);
}
__device__ __forceinline__ float fast_silu(float v){
  return v * __builtin_amdgcn_rcpf(1.f + __expf(-v));
}
// XOR-swizzled LDS addressing for 64x(256 bf16) tiles (512B rows).
__device__ __forceinline__ void* swz(void* base, int row, int byteoff){
  return (void*)((char*)base + (row<<9) + (byteoff ^ ((row&7)<<4)));
}
// FFT LDS swizzle on float2 index.
#define SW(i) ((i) ^ (((i)>>4)&15))
// base-4 digit reversal of a 12-bit index (6 digits).
__device__ __forceinline__ int rev4(int k){
  return ((k&3)<<10) | (((k>>2)&3)<<8) | (((k>>4)&3)<<6)
       | (((k>>6)&3)<<4) | (((k>>8)&3)<<2) | ((k>>10)&3);
}

// ---------------- prep: fragment-major bf16 weights (Wd+Wbc, Wg, W_in), twiddles ----------------
__global__ void k_prep(const float* Wd, const float* Wg, const float* WB, const float* WC,
                       const float* W_in, const float* bBv, const float* bCv,
                       unsigned short* WdF, unsigned short* WgF, unsigned short* WinF,
                       float* bbc, float2* tw){
  int id = blockIdx.x*256 + threadIdx.x;
  if (id < 73728){
    int jn = id >> 12; int rem = id & 4095;
    int kc = rem >> 9; int l8 = (rem >> 3) & 63; int e = id & 7;
    int lr = l8 & 15, lh = l8 >> 4;
    int k = kc*32 + lh*8 + e;
    float v;
    if (jn < 16){ int n = jn*16 + lr; v = Wd[k*256+n]; }
    else { int c = (jn-16)*16 + lr; v = (c<16) ? WB[k*16+c] : WC[k*16+(c-16)]; }
    WdF[id] = f2bf(v);
  }
  else if (id < 139264){
    int o = id - 73728;
    int jn = o >> 12; int rem = o & 4095;
    int kc = rem >> 9; int l8 = (rem >> 3) & 63; int e = o & 7;
    int lr = l8 & 15, lh = l8 >> 4;
    int k = kc*32 + lh*8 + e;
    WgF[o] = f2bf(Wg[k*256 + jn*16 + lr]);
  }
  else if (id < 155648){
    int o = id - 139264;
    int jn = o >> 10; int rem = o & 1023;
    int kc = rem >> 9; int l8 = (rem >> 3) & 63; int e = o & 7;
    int lr = l8 & 15, lh = l8 >> 4;
    int k = kc*32 + lh*8 + e;
    WinF[o] = f2bf(W_in[k*256 + jn*16 + lr]);
  }
  else if (id < 157696){ int k = id-155648;
    double a = -6.283185307179586476925287 * (double)k / 4096.0;
    tw[k] = make_float2((float)cos(a), (float)sin(a)); }
  else if (id < 157728){ int j = id-157696; bbc[j] = (j<16)? bBv[j] : bCv[j-16]; }
}

// ---------------- fused front-end: MFMA xp GEMM + transposed xpz write + LN + conv + silu ----------------
__global__ __launch_bounds__(256) void k_front(const float* x, const unsigned short* WinF, const float* b_in,
      const float* ln1_g, const float* ln1_b, const float* conv_w, const float* conv_b,
      float2* xpz, unsigned short* xn16, unsigned short* u16){
  __shared__ unsigned short xb[32*64];
  __shared__ float xs[20][260];
  int tid = threadIdx.x;
  int b = blockIdx.y; int t0 = blockIdx.x*16;
  {
    int row = tid>>3, slot = tid&7;
    int t = t0 - 1 + row;
    unsigned short h[8];
    if (row < 18 && t >= 0 && t < SS){
      const float* src = &x[((size_t)b*SS + t)*IN + slot*8];
      float4 v0 = *(const float4*)src;
      float4 v1 = *(const float4*)(src+4);
      h[0]=f2bf(v0.x); h[1]=f2bf(v0.y); h[2]=f2bf(v0.z); h[3]=f2bf(v0.w);
      h[4]=f2bf(v1.x); h[5]=f2bf(v1.y); h[6]=f2bf(v1.z); h[7]=f2bf(v1.w);
    } else {
      #pragma unroll
      for (int i=0;i<8;i++) h[i]=0;
    }
    *(uint4*)&xb[row*64 + ((slot ^ (row&7))<<3)] = *(uint4*)h;
  }
  __syncthreads();
  int wv = tid>>6, lane = tid&63, lr = lane&15, lh = lane>>4;
  {
    bf16x8 af[2][2];
    #pragma unroll
    for (int rf=0;rf<2;rf++)
      #pragma unroll
      for (int kc=0;kc<2;kc++){
        int row = rf*16 + lr;
        int slot = (kc*4 + lh) ^ (row&7);
        af[rf][kc] = *(const bf16x8*)&xb[row*64 + slot*8];
      }
    f32x4 acc[2][4];
    #pragma unroll
    for (int rf=0;rf<2;rf++)
      #pragma unroll
      for (int jj=0;jj<4;jj++){ acc[rf][jj][0]=0.f; acc[rf][jj][1]=0.f; acc[rf][jj][2]=0.f; acc[rf][jj][3]=0.f; }
    #pragma unroll
    for (int jj=0;jj<4;jj++){
      int jn = wv*4 + jj;
      const bf16x8* bp = (const bf16x8*)(WinF + (size_t)jn*1024 + (size_t)lane*8);
      bf16x8 b0 = bp[0];
      bf16x8 b1 = bp[64];
      #pragma unroll
      for (int rf=0;rf<2;rf++){
        acc[rf][jj] = __builtin_amdgcn_mfma_f32_16x16x32_bf16(af[rf][0], b0, acc[rf][jj], 0,0,0);
        acc[rf][jj] = __builtin_amdgcn_mfma_f32_16x16x32_bf16(af[rf][1], b1, acc[rf][jj], 0,0,0);
      }
    }
    #pragma unroll
    for (int jj=0;jj<4;jj++){
      int col = (wv*4+jj)*16 + lr;
      float bs = b_in[col];
      #pragma unroll
      for (int rf=0;rf<2;rf++){
        #pragma unroll
        for (int i=0;i<4;i++){
          int row = rf*16 + lh*4 + i;
          if (row < 18) xs[row][col] = acc[rf][jj][i] + bs;
        }
      }
    }
  }
  __syncthreads();
  {
    int sl = tid&15, p0 = tid>>4;
    float2* dst = xpz + (size_t)b*128*SS + t0 + sl;
    #pragma unroll
    for (int pass=0; pass<8; pass++){
      int p = p0 + 16*pass;
      float2 v = *(const float2*)&xs[1+sl][2*p];
      dst[(size_t)p*SS] = v;
    }
  }
  __syncthreads();
  float4 lg4 = *(const float4*)&ln1_g[lane*4];
  float4 lb4 = *(const float4*)&ln1_b[lane*4];
  for (int r=wv; r<18; r+=4){
    int t = t0 - 1 + r;
    bool valid = (t>=0) && (t<SS);
    float4 v = *(const float4*)&xs[r][lane*4];
    float s1 = v.x+v.y+v.z+v.w;
    float s2 = v.x*v.x+v.y*v.y+v.z*v.z+v.w*v.w;
    #pragma unroll
    for (int off=32; off; off>>=1){ s1 += __shfl_xor(s1,off); s2 += __shfl_xor(s2,off); }
    float mean = s1*(1.f/256.f);
    float var  = s2*(1.f/256.f) - mean*mean;
    float rstd = rsqrtf(var + 1e-5f);
    float o0 = valid ? ((v.x-mean)*rstd*lg4.x + lb4.x) : 0.f;
    float o1 = valid ? ((v.y-mean)*rstd*lg4.y + lb4.y) : 0.f;
    float o2 = valid ? ((v.z-mean)*rstd*lg4.z + lb4.z) : 0.f;
    float o3 = valid ? ((v.w-mean)*rstd*lg4.w + lb4.w) : 0.f;
    *(float4*)&xs[r][lane*4] = make_float4(o0,o1,o2,o3);
    if (r>=1 && r<=16){
      ushort4 st;
      st.x=f2bf(o0); st.y=f2bf(o1); st.z=f2bf(o2); st.w=f2bf(o3);
      *(ushort4*)&xn16[((size_t)b*SS + t)*DD + lane*4] = st;
    }
  }
  __syncthreads();
  int d = tid;
  float w0=conv_w[d*3], w1=conv_w[d*3+1], w2=conv_w[d*3+2], cb=conv_b[d];
  #pragma unroll 4
  for (int rr=0; rr<16; rr++){
    float a0=xs[rr][d], a1=xs[rr+1][d], a2=xs[rr+2][d];
    float xc = a0*w0 + a1*w1 + a2*w2 + cb;
    u16[((size_t)b*SS + (t0+rr))*DD + d] = f2bf(fast_silu(xc));
  }
}

// ---------------- fused single-pass GEMM: 64 rows x all-N, A in LDS, frag-major B from L2 ----------------
// ACT==1 (u -> delta): writes t-paired de2/du2 (uint: 2 bf16 per word) + bc16.
// ACT==2 (xn -> g): writes t-paired g2.
template<int NTOT, int ACT>
__global__ __launch_bounds__(512,2) void k_gemm2(const unsigned short* Ab, const unsigned short* Bt,
      const float* bias_main, const float* bias_bc,
      unsigned int* out2, unsigned int* du2, unsigned short* out_bc){
  __shared__ unsigned short As[64*256];   // 32 KiB
  const int NF = NTOT/2;
  int tid = threadIdx.x;
  int m0 = blockIdx.x*64;
  {
    const uint4* gA = (const uint4*)(Ab + (size_t)m0*256);
    #pragma unroll
    for (int i=0;i<4;i++){
      int f = tid + 512*i;
      uint4 v = gA[f];
      *(uint4*)swz(As, f>>5, (f&31)<<4) = v;
    }
  }
  __syncthreads();
  int wv = tid>>6, lane = tid&63;
  int wm = wv>>1, nh = wv&1;
  int lr = lane&15, lh = lane>>4;
  const bf16x8* bbase = (const bf16x8*)(Bt + (size_t)(nh*NF)*4096 + (size_t)lane*8);
  bf16x8 af[8];
  #pragma unroll
  for (int kc=0;kc<8;kc++)
    af[kc] = *(const bf16x8*)swz(As, wm*16+lr, kc*64+lh*16);
  f32x4 acc[NF];
  #pragma unroll
  for (int j=0;j<NF;j++){ acc[j][0]=0.f; acc[j][1]=0.f; acc[j][2]=0.f; acc[j][3]=0.f; }
  bf16x8 bq[2][8];
  #pragma unroll
  for (int kc=0;kc<8;kc++) bq[0][kc] = bbase[kc*64];
  #pragma unroll
  for (int j=0;j<NF;j++){
    if (j+1 < NF){
      #pragma unroll
      for (int kc=0;kc<8;kc++) bq[(j+1)&1][kc] = bbase[(j+1)*512 + kc*64];
    }
    #pragma unroll
    for (int kc=0;kc<8;kc++){
      acc[j] = __builtin_amdgcn_mfma_f32_16x16x32_bf16(af[kc], bq[j&1][kc], acc[j], 0,0,0);
    }
  }
  int row0 = m0 + wm*16 + lh*4;           // global flat row (b*4096+t), t multiple of 4
  size_t pbase = ((size_t)row0 >> 1) * 256;   // pair index * 256
  #pragma unroll
  for (int j=0;j<NF;j++){
    int jn = nh*NF + j;
    if (jn < 16){
      int col = jn*16 + lr;
      float bs = bias_main[col];
      if (ACT==1){
        float de[4], du[4];
        #pragma unroll
        for (int i=0;i<4;i++){
          de[i] = fast_softplus(acc[j][i] + bs);
          float uu = bf2f(*(const unsigned short*)swz(As, wm*16+lh*4+i, col*2));
          du[i] = de[i]*uu;
        }
        out2[pbase + col]       = (unsigned int)f2bf(de[0]) | ((unsigned int)f2bf(de[1])<<16);
        out2[pbase + 256 + col] = (unsigned int)f2bf(de[2]) | ((unsigned int)f2bf(de[3])<<16);
        du2 [pbase + col]       = (unsigned int)f2bf(du[0]) | ((unsigned int)f2bf(du[1])<<16);
        du2 [pbase + 256 + col] = (unsigned int)f2bf(du[2]) | ((unsigned int)f2bf(du[3])<<16);
      } else {
        float g[4];
        #pragma unroll
        for (int i=0;i<4;i++) g[i] = fast_silu(acc[j][i] + bs);
        out2[pbase + col]       = (unsigned int)f2bf(g[0]) | ((unsigned int)f2bf(g[1])<<16);
        out2[pbase + 256 + col] = (unsigned int)f2bf(g[2]) | ((unsigned int)f2bf(g[3])<<16);
      }
    } else {
      int col = (jn-16)*16 + lr;
      float bs = bias_bc[col];
      #pragma unroll
      for (int i=0;i<4;i++){
        int row = m0 + wm*16 + lh*4 + i;
        out_bc[(size_t)row*32 + col] = f2bf(acc[j][i] + bs);
      }
    }
  }
}

// ---------------- FFT: two-for-one 4096-pt in-place radix-4 DIF; DC rank + T0 ----------------
__global__ __launch_bounds__(256,4) void k_fft(const float2* xpz, const float2* twg, int* rank, float* T0){
  __shared__ float2 buf[4096];
  __shared__ int scr8[8];
  int blk = blockIdx.x;
  int b = blk >> 7, pair = blk & 127;
  int tid = threadIdx.x;
  const float4* src4 = (const float4*)(xpz + ((size_t)b*128 + pair)*SS);
  #pragma unroll
  for (int q=tid; q<2048; q+=256){
    float4 v = src4[q];
    buf[SW(2*q)]   = make_float2(v.x, v.y);
    buf[SW(2*q+1)] = make_float2(v.z, v.w);
  }
  __syncthreads();
  int m = 1024, fac = 1;
  for (int st=0; st<6; st++){
    #pragma unroll
    for (int it=0; it<4; it++){
      int t = tid + 256*it;
      int j = t & (m-1);
      int i0 = 4*t - 3*j;
      float2 a0 = buf[SW(i0)];
      float2 a1 = buf[SW(i0+m)];
      float2 a2 = buf[SW(i0+2*m)];
      float2 a3 = buf[SW(i0+3*m)];
      float2 w1 = twg[j*fac];
      float2 w2 = make_float2(fmaf(w1.x,w1.x,-w1.y*w1.y), 2.f*w1.x*w1.y);
      float2 w3 = make_float2(fmaf(w1.x,w2.x,-w1.y*w2.y), fmaf(w1.x,w2.y, w1.y*w2.x));
      float t0x=a0.x+a2.x, t0y=a0.y+a2.y;
      float t1x=a0.x-a2.x, t1y=a0.y-a2.y;
      float t2x=a1.x+a3.x, t2y=a1.y+a3.y;
      float t3x=a1.y-a3.y, t3y=a3.x-a1.x;
      buf[SW(i0)]     = make_float2(t0x+t2x, t0y+t2y);
      float b1x = t1x+t3x, b1y = t1y+t3y;
      buf[SW(i0+m)]   = make_float2(fmaf(w1.x,b1x,-w1.y*b1y), fmaf(w1.x,b1y, w1.y*b1x));
      float b2x = t0x-t2x, b2y = t0y-t2y;
      buf[SW(i0+2*m)] = make_float2(fmaf(w2.x,b2x,-w2.y*b2y), fmaf(w2.x,b2y, w2.y*b2x));
      float b3x = t1x-t3x, b3y = t1y-t3y;
      buf[SW(i0+3*m)] = make_float2(fmaf(w3.x,b3x,-w3.y*b3y), fmaf(w3.x,b3y, w3.y*b3x));
    }
    __syncthreads();
    m >>= 2; fac <<= 2;
  }
  float2 z0 = buf[0];
  float thx = 4.f*z0.x*z0.x, thy = 4.f*z0.y*z0.y;
  int cx=0, cy=0;
  #pragma unroll
  for (int j=0;j<8;j++){
    int f = 1 + tid + 256*j;
    float2 zf = buf[SW(rev4(f))];
    float2 zc = buf[SW(rev4(4096-f))];
    float sxr = zf.x+zc.x, sxi = zf.y-zc.y;
    float syr = zf.x-zc.x, syi = zf.y+zc.y;
    cx += (fmaf(sxr,sxr,sxi*sxi) > thx) ? 1 : 0;
    cy += (fmaf(syr,syr,syi*syi) > thy) ? 1 : 0;
  }
  #pragma unroll
  for (int off=32; off; off>>=1){ cx += __shfl_xor(cx, off); cy += __shfl_xor(cy, off); }
  if ((tid&63)==0){ scr8[tid>>6] = cx; scr8[4+(tid>>6)] = cy; }
  __syncthreads();
  if (tid==0){
    int r0 = b*256 + 2*pair;
    rank[r0]   = scr8[0]+scr8[1]+scr8[2]+scr8[3];
    rank[r0+1] = scr8[4]+scr8[5]+scr8[6]+scr8[7];
    T0[r0]   = z0.x;
    T0[r0+1] = z0.y;
  }
}

// ---------------- scan pass A (d x n-half, f32 LDS bm, t-paired loads) ----------------
__global__ __launch_bounds__(512) void k_scanA(const unsigned int* de2, const unsigned int* du2,
      const unsigned short* bc16, const float* Aw, float* AB_A, float* AB_B){
  __shared__ float bcs[LCH][16];
  int c = blockIdx.x, b = blockIdx.y;
  int t0 = c*LCH;
  int tid = threadIdx.x;
  {
    int t = tid>>3, q = tid&7;
    unsigned int v = *(const unsigned int*)(bc16 + ((size_t)b*SS + t0 + t)*32 + q*2);
    bcs[t][q*2]   = bf2f((unsigned short)(v & 0xffff));
    bcs[t][q*2+1] = bf2f((unsigned short)(v >> 16));
  }
  __syncthreads();
  int d = tid & 255, hf = tid >> 8;
  float aw[8];
  #pragma unroll
  for (int j=0;j<2;j++){
    float4 a4 = *(const float4*)&Aw[d*16 + hf*8 + j*4];
    aw[4*j]=a4.x; aw[4*j+1]=a4.y; aw[4*j+2]=a4.z; aw[4*j+3]=a4.w;
  }
  float Ac[8], Bc[8];
  #pragma unroll
  for (int n=0;n<8;n++){ Ac[n]=1.f; Bc[n]=0.f; }
  const unsigned int* DE = de2 + ((size_t)b*2048 + c*32)*256 + d;
  const unsigned int* DU = du2 + ((size_t)b*2048 + c*32)*256 + d;
  #pragma unroll 4
  for (int p=0;p<32;p++){
    unsigned int dv = DE[(size_t)p*256];
    unsigned int uv = DU[(size_t)p*256];
    float de0 = __uint_as_float(dv<<16);
    float de1 = __uint_as_float(dv&0xffff0000u);
    float du0 = __uint_as_float(uv<<16);
    float du1 = __uint_as_float(uv&0xffff0000u);
    {
      float4 B0 = *(const float4*)&bcs[2*p][hf*8];
      float4 B1 = *(const float4*)&bcs[2*p][hf*8+4];
      float bm[8] = {B0.x,B0.y,B0.z,B0.w, B1.x,B1.y,B1.z,B1.w};
      #pragma unroll
      for (int n=0;n<8;n++){
        float a = fmaf(de0, aw[n], 1.f);
        Ac[n] *= a;
        Bc[n] = fmaf(a, Bc[n], du0*bm[n]);
      }
    }
    {
      float4 B0 = *(const float4*)&bcs[2*p+1][hf*8];
      float4 B1 = *(const float4*)&bcs[2*p+1][hf*8+4];
      float bm[8] = {B0.x,B0.y,B0.z,B0.w, B1.x,B1.y,B1.z,B1.w};
      #pragma unroll
      for (int n=0;n<8;n++){
        float a = fmaf(de1, aw[n], 1.f);
        Ac[n] *= a;
        Bc[n] = fmaf(a, Bc[n], du1*bm[n]);
      }
    }
  }
  size_t o = (size_t)c*65536 + (size_t)b*4096 + (size_t)d*16 + hf*8;
  #pragma unroll
  for (int j=0;j<2;j++){
    *(float4*)&AB_A[o+4*j] = make_float4(Ac[4*j],Ac[4*j+1],Ac[4*j+2],Ac[4*j+3]);
    *(float4*)&AB_B[o+4*j] = make_float4(Bc[4*j],Bc[4*j+1],Bc[4*j+2],Bc[4*j+3]);
  }
}

// ---------------- scan pass B: prefix over chunks ----------------
__global__ void k_scanB(const float* AB_A, const float* AB_B, float* Hs){
  int tid = blockIdx.x*256 + threadIdx.x;
  float h = 0.f;
  #pragma unroll 8
  for (int c=0;c<CH;c++){
    Hs[c*65536 + tid] = h;
    h = fmaf(AB_A[c*65536 + tid], h, AB_B[c*65536 + tid]);
  }
}

// ---------------- scan pass C (d x n-half, f32 LDS bm/cm, t-paired loads) ----------------
__global__ __launch_bounds__(512) void k_scanC(const unsigned int* de2, const unsigned int* du2,
      const unsigned int* g2, const unsigned short* bc16, const float* Aw, const float* Hs, float* part){
  __shared__ float bcs[LCH][32];
  __shared__ float scr[256];
  int c = blockIdx.x, b = blockIdx.y;
  int t0 = c*LCH;
  int tid = threadIdx.x;
  {
    int t = tid>>3, q = tid&7;
    uint2 v = *(const uint2*)(bc16 + ((size_t)b*SS + t0 + t)*32 + q*4);
    bcs[t][q*4]   = bf2f((unsigned short)(v.x & 0xffff));
    bcs[t][q*4+1] = bf2f((unsigned short)(v.x >> 16));
    bcs[t][q*4+2] = bf2f((unsigned short)(v.y & 0xffff));
    bcs[t][q*4+3] = bf2f((unsigned short)(v.y >> 16));
  }
  __syncthreads();
  int d = tid & 255, hf = tid >> 8;
  float aw[8];
  #pragma unroll
  for (int j=0;j<2;j++){
    float4 a4 = *(const float4*)&Aw[d*16 + hf*8 + j*4];
    aw[4*j]=a4.x; aw[4*j+1]=a4.y; aw[4*j+2]=a4.z; aw[4*j+3]=a4.w;
  }
  float h[8];
  {
    size_t o = (size_t)c*65536 + (size_t)b*4096 + (size_t)d*16 + hf*8;
    #pragma unroll
    for (int j=0;j<2;j++){
      float4 h4 = *(const float4*)&Hs[o+4*j];
      h[4*j]=h4.x; h[4*j+1]=h4.y; h[4*j+2]=h4.z; h[4*j+3]=h4.w;
    }
  }
  float acc = 0.f;
  const unsigned int* DE = de2 + ((size_t)b*2048 + c*32)*256 + d;
  const unsigned int* DU = du2 + ((size_t)b*2048 + c*32)*256 + d;
  const unsigned int* G  = g2  + ((size_t)b*2048 + c*32)*256 + d;
  #pragma unroll 4
  for (int p=0;p<32;p++){
    unsigned int dv = DE[(size_t)p*256];
    unsigned int uv = DU[(size_t)p*256];
    unsigned int gv = G [(size_t)p*256];
    float de0 = __uint_as_float(dv<<16);
    float de1 = __uint_as_float(dv&0xffff0000u);
    float du0 = __uint_as_float(uv<<16);
    float du1 = __uint_as_float(uv&0xffff0000u);
    float gg0 = __uint_as_float(gv<<16);
    float gg1 = __uint_as_float(gv&0xffff0000u);
    {
      float4 B0 = *(const float4*)&bcs[2*p][hf*8];
      float4 B1 = *(const float4*)&bcs[2*p][hf*8+4];
      float4 C0 = *(const float4*)&bcs[2*p][16+hf*8];
      float4 C1 = *(const float4*)&bcs[2*p][16+hf*8+4];
      float bm[8] = {B0.x,B0.y,B0.z,B0.w, B1.x,B1.y,B1.z,B1.w};
      float cm[8] = {C0.x,C0.y,C0.z,C0.w, C1.x,C1.y,C1.z,C1.w};
      float y0 = 0.f, y1 = 0.f;
      #pragma unroll
      for (int n=0;n<8;n+=2){
        float a0 = fmaf(de0, aw[n],   1.f);
        float a1 = fmaf(de0, aw[n+1], 1.f);
        h[n]   = fmaf(a0, h[n],   du0*bm[n]);
        h[n+1] = fmaf(a1, h[n+1], du0*bm[n+1]);
        y0 = fmaf(cm[n],   h[n],   y0);
        y1 = fmaf(cm[n+1], h[n+1], y1);
      }
      acc = fmaf(y0+y1, gg0, acc);
    }
    {
      float4 B0 = *(const float4*)&bcs[2*p+1][hf*8];
      float4 B1 = *(const float4*)&bcs[2*p+1][hf*8+4];
      float4 C0 = *(const float4*)&bcs[2*p+1][16+hf*8];
      float4 C1 = *(const float4*)&bcs[2*p+1][16+hf*8+4];
      float bm[8] = {B0.x,B0.y,B0.z,B0.w, B1.x,B1.y,B1.z,B1.w};
      float cm[8] = {C0.x,C0.y,C0.z,C0.w, C1.x,C1.y,C1.z,C1.w};
      float y0 = 0.f, y1 = 0.f;
      #pragma unroll
      for (int n=0;n<8;n+=2){
        float a0 = fmaf(de1, aw[n],   1.f);
        float a1 = fmaf(de1, aw[n+1], 1.f);
        h[n]   = fmaf(a0, h[n],   du1*bm[n]);
        h[n+1] = fmaf(a1, h[n+1], du1*bm[n+1]);
        y0 = fmaf(cm[n],   h[n],   y0);
        y1 = fmaf(cm[n+1], h[n+1], y1);
      }
      acc = fmaf(y0+y1, gg1, acc);
    }
  }
  if (hf==1) scr[d] = acc;
  __syncthreads();
  if (hf==0) part[(size_t)(b*256 + d)*CH + c] = acc + scr[d];
}

// ---------------- final: zp assembly + LN + 2-layer MLP ----------------
__global__ __launch_bounds__(256) void k_final(const float* part, const float* T0, const int* rank,
      const float* alpha, const float* beta, const float* filt_re,
      const float* lnc_g, const float* lnc_b,
      const float* W1, const float* b1, const float* W2, const float* b2,
      float* out){
  __shared__ float zs[256];
  __shared__ float h1[128];
  __shared__ float red[8];
  int b = blockIdx.x, d = threadIdx.x;
  int row = b*256 + d;
  float ps = 0.f;
  #pragma unroll 8
  for (int c=0;c<CH;c++) ps += part[(size_t)row*CH + c];
  float ssm_mean = ps * (1.f/4096.f);
  float t0v = T0[row];
  float mxp = t0v * (1.f/4096.f);
  int r = rank[row];
  float spec = (r < KK) ? t0v * filt_re[r*DD + d] * (1.f/4096.f) : 0.f;
  float zp = alpha[d]*(mxp + ssm_mean) + beta[d]*spec;
  float s1 = zp, s2 = zp*zp;
  #pragma unroll
  for (int off=32; off; off>>=1){ s1 += __shfl_xor(s1,off); s2 += __shfl_xor(s2,off); }
  if ((d&63)==0){ red[d>>6] = s1; red[4+(d>>6)] = s2; }
  __syncthreads();
  float mean = (red[0]+red[1]+red[2]+red[3]) * (1.f/256.f);
  float var  = (red[4]+red[5]+red[6]+red[7]) * (1.f/256.f) - mean*mean;
  float ln = (zp-mean)*rsqrtf(var+1e-5f)*lnc_g[d] + lnc_b[d];
  zs[d] = ln;
  __syncthreads();
  if (d < 128){
    float acc = b1[d];
    #pragma unroll 16
    for (int k=0;k<256;k++) acc = fmaf(zs[k], W1[k*128+d], acc);
    h1[d] = fmaxf(acc, 0.f);
  }
  __syncthreads();
  if (d < 2){
    float acc = b2[d];
    #pragma unroll 16
    for (int k=0;k<128;k++) acc = fmaf(h1[k], W2[k*2+d], acc);
    out[b*2+d] = acc;
  }
}

extern "C" void kernel_launch(void* const* d_in, const int* in_sizes, int n_in,
                              void* d_out, int out_size, void* d_ws, size_t ws_size,
                              hipStream_t stream){
  const float* x      = (const float*)d_in[0];
  const float* W_in   = (const float*)d_in[1];
  const float* b_in   = (const float*)d_in[2];
  const float* ln1_g  = (const float*)d_in[3];
  const float* ln1_b  = (const float*)d_in[4];
  const float* conv_w = (const float*)d_in[5];
  const float* conv_b = (const float*)d_in[6];
  const float* Wd     = (const float*)d_in[7];
  const float* bd     = (const float*)d_in[8];
  const float* WB     = (const float*)d_in[9];
  const float* bB     = (const float*)d_in[10];
  const float* WC     = (const float*)d_in[11];
  const float* bC     = (const float*)d_in[12];
  const float* A      = (const float*)d_in[13];
  const float* Wg     = (const float*)d_in[14];
  const float* bg     = (const float*)d_in[15];
  const float* filt_re= (const float*)d_in[16];
  const float* alpha  = (const float*)d_in[18];
  const float* beta   = (const float*)d_in[19];
  const float* lnc_g  = (const float*)d_in[20];
  const float* lnc_b  = (const float*)d_in[21];
  const float* W1     = (const float*)d_in[22];
  const float* b1     = (const float*)d_in[23];
  const float* W2     = (const float*)d_in[24];
  const float* b2     = (const float*)d_in[25];

  char* w = (char*)d_ws;
  unsigned int* de2 = (unsigned int*)(w);
  unsigned int* du2 = (unsigned int*)(w + 33554432);
  float2* xpz = (float2*)(w + 67108864);
  float* AB_A = (float*)(w + 67108864);
  float* AB_B = (float*)(w + 67108864 + 16777216);
  float* Hs   = (float*)(w + 67108864 + 33554432);
  unsigned short* bc16 = (unsigned short*)(w + 67108864 + 50331648);
  float* part = (float*)(w + 67108864 + 54525952);
  unsigned short* xn16 = (unsigned short*)(w + 134217728);
  unsigned short* u16  = (unsigned short*)(w + 167772160);
  unsigned int* g2 = (unsigned int*)(w + 201326592);
  char* small = w + 234881024;
  unsigned short* WdF  = (unsigned short*)(small);
  unsigned short* WgF  = (unsigned short*)(small + 147456);
  unsigned short* WinF = (unsigned short*)(small + 278528);
  float*  bbc = (float*)(small + 311296);
  float2* tw  = (float2*)(small + 311424);
  float*  T0  = (float*)(small + 327808);
  int*    rank= (int*)(small + 344192);
  (void)in_sizes; (void)n_in; (void)out_size; (void)ws_size;

  hipLaunchKernelGGL(k_prep, dim3(617), dim3(256), 0, stream,
                     Wd, Wg, WB, WC, W_in, bB, bC, WdF, WgF, WinF, bbc, tw);
  hipLaunchKernelGGL(k_front, dim3(SS/16, BB), dim3(256), 0, stream,
                     x, WinF, b_in, ln1_g, ln1_b, conv_w, conv_b, xpz, xn16, u16);
  hipLaunchKernelGGL(k_fft, dim3(BB*128), dim3(256), 0, stream, xpz, tw, rank, T0);
  hipLaunchKernelGGL((k_gemm2<18,1>), dim3(BS/64), dim3(512), 0, stream,
                     u16, WdF, bd, bbc, de2, du2, bc16);
  hipLaunchKernelGGL((k_gemm2<16,2>), dim3(BS/64), dim3(512), 0, stream,
                     xn16, WgF, bg, bbc, g2, (unsigned int*)nullptr, bc16);
  hipLaunchKernelGGL(k_scanA, dim3(CH, BB), dim3(512), 0, stream, de2, du2, bc16, A, AB_A, AB_B);
  hipLaunchKernelGGL(k_scanB, dim3(256), dim3(256), 0, stream, AB_A, AB_B, Hs);
  hipLaunchKernelGGL(k_scanC, dim3(CH, BB), dim3(512), 0, stream, de2, du2, g2, bc16, A, Hs, part);
  hipLaunchKernelGGL(k_final, dim3(BB), dim3(256), 0, stream,
                     part, T0, rank, alpha, beta, filt_re, lnc_g, lnc_b, W1, b1, W2, b2, (float*)d_out);
}